// Round 2
// baseline (3390.210 us; speedup 1.0000x reference)
//
#include <hip/hip_runtime.h>

#define H 1024
#define ITR 2048
#define NE 8

typedef __attribute__((ext_vector_type(8))) short short8;
typedef __attribute__((ext_vector_type(4))) float f32x4;

__device__ __forceinline__ float bf2f(unsigned short u){
  union { unsigned int i; float f; } v; v.i = ((unsigned int)u) << 16; return v.f;
}
__device__ __forceinline__ unsigned short f2bf(float f){
  union { unsigned int i; float f; } v; v.f = f;
  unsigned int r = v.i + 0x7FFFu + ((v.i >> 16) & 1u);
  return (unsigned short)(r >> 16);
}
__device__ __forceinline__ void gload16(const void* g, void* l){
  __builtin_amdgcn_global_load_lds((const __attribute__((address_space(1))) void*)g,
                                   (__attribute__((address_space(3))) void*)l, 16, 0, 0);
}

// ---- dtype probe: bf16 data => even-index ushorts have sane exponents (~100%);
// ---- f32 data => even-index ushorts are mantissa bits (~16% sane). flag=1 => f32.
__global__ __launch_bounds__(64) void detect_k(const unsigned int* __restrict__ xw,
                                               int* __restrict__ flag, int* __restrict__ counts){
  int lane = threadIdx.x;
  int c = 0;
  #pragma unroll
  for (int i = 0; i < 4; i++){
    unsigned u = xw[lane * 4 + i];
    int e = (u >> 7) & 0xFF;           // exponent field of the LOW ushort viewed as bf16
    c += (e >= 100 && e <= 140) ? 1 : 0;
  }
  #pragma unroll
  for (int off = 32; off; off >>= 1) c += __shfl_xor(c, off);
  if (lane == 0) flag[0] = (c < 128) ? 1 : 0;
  if (lane < NE) counts[lane] = 0;
}

// ---- load 16 consecutive elements as f32 regardless of storage dtype ----
__device__ __forceinline__ void loadv16(const void* base, size_t off, int isf, float* out){
  if (isf){
    const float* p = (const float*)base + off;
    float4 a = *(const float4*)p, b = *(const float4*)(p + 4);
    float4 c = *(const float4*)(p + 8), d = *(const float4*)(p + 12);
    out[0]=a.x; out[1]=a.y; out[2]=a.z; out[3]=a.w;
    out[4]=b.x; out[5]=b.y; out[6]=b.z; out[7]=b.w;
    out[8]=c.x; out[9]=c.y; out[10]=c.z; out[11]=c.w;
    out[12]=d.x; out[13]=d.y; out[14]=d.z; out[15]=d.w;
  } else {
    const unsigned short* p = (const unsigned short*)base + off;
    uint4 a = *(const uint4*)p, b = *(const uint4*)(p + 8);
    unsigned short u[16];
    *(uint4*)u = a; *(uint4*)(u + 8) = b;
    #pragma unroll
    for (int j = 0; j < 16; j++) out[j] = bf2f(u[j]);
  }
}

// ---- transpose one expert's 3 matrices -> bf16, z: 0=gate(HxI), 1=up(HxI), 2=down(IxH) ----
__global__ __launch_bounds__(256) void trans3_k(const void* __restrict__ gs, const void* __restrict__ us,
                                                const void* __restrict__ dsrc, size_t eoff,
                                                unsigned short* __restrict__ gT, unsigned short* __restrict__ uT,
                                                unsigned short* __restrict__ dT, const int* __restrict__ flag){
  int z = blockIdx.z;
  int R = (z == 2) ? ITR : H;
  int C = (z == 2) ? H : ITR;
  int c0 = blockIdx.x * 64, r0 = blockIdx.y * 64;
  if (c0 >= C || r0 >= R) return;
  const void* srcv = (z == 0) ? gs : ((z == 1) ? us : dsrc);
  unsigned short* dst = (z == 0) ? gT : ((z == 1) ? uT : dT);
  int isf = *flag;
  __shared__ unsigned short tile[64][72];
  int t = threadIdx.x;
  int row = t >> 3, c8 = (t & 7) * 8;
  #pragma unroll
  for (int p = 0; p < 2; p++){
    int r = r0 + row + p * 32;
    unsigned short v[8];
    if (isf){
      const float* s = (const float*)srcv + eoff + (size_t)r * C + c0 + c8;
      float4 a = *(const float4*)s, b = *(const float4*)(s + 4);
      v[0]=f2bf(a.x); v[1]=f2bf(a.y); v[2]=f2bf(a.z); v[3]=f2bf(a.w);
      v[4]=f2bf(b.x); v[5]=f2bf(b.y); v[6]=f2bf(b.z); v[7]=f2bf(b.w);
    } else {
      const unsigned short* s = (const unsigned short*)srcv + eoff + (size_t)r * C + c0 + c8;
      *(uint4*)v = *(const uint4*)s;
    }
    *(uint4*)&tile[row + p * 32][c8] = *(const uint4*)v;
  }
  __syncthreads();
  #pragma unroll
  for (int p = 0; p < 2; p++){
    int c = row + p * 32;
    unsigned short tmp[8];
    #pragma unroll
    for (int j = 0; j < 8; j++) tmp[j] = tile[c8 + j][c];
    *(uint4*)(dst + (size_t)(c0 + c) * R + r0 + c8) = *(const uint4*)tmp;
  }
}

// ---- router over all T tokens ----
__global__ __launch_bounds__(256) void router_k(
    const void* __restrict__ x, const void* __restrict__ lns, const void* __restrict__ lnb,
    const void* __restrict__ gw, int T, const int* __restrict__ flag,
    int* __restrict__ counts, int* __restrict__ lidx, float* __restrict__ lw)
{
  int isf = *flag;
  int wv = threadIdx.x >> 6, lane = threadIdx.x & 63;
  int tok = blockIdx.x * 4 + wv;
  if (tok >= T) return;
  float v[16];
  loadv16(x, (size_t)tok * H + lane * 16, isf, v);
  float sum = 0.f, ss = 0.f;
  #pragma unroll
  for (int j = 0; j < 16; j++){ sum += v[j]; ss += v[j] * v[j]; }
  #pragma unroll
  for (int off = 32; off; off >>= 1){ sum += __shfl_xor(sum, off); ss += __shfl_xor(ss, off); }
  float mu = sum * (1.f / H);
  float rstd = rsqrtf(ss * (1.f / H) - mu * mu + 1e-5f);
  float sc[16], bi[16], xn[16];
  loadv16(lns, (size_t)lane * 16, isf, sc);
  loadv16(lnb, (size_t)lane * 16, isf, bi);
  #pragma unroll
  for (int j = 0; j < 16; j++) xn[j] = (v[j] - mu) * rstd * sc[j] + bi[j];
  float acc[NE];
  #pragma unroll
  for (int e = 0; e < NE; e++){
    float g[16];
    loadv16(gw, (size_t)e * H + lane * 16, isf, g);
    float s = 0.f;
    #pragma unroll
    for (int j = 0; j < 16; j++) s += xn[j] * g[j];
    acc[e] = s;
  }
  #pragma unroll
  for (int off = 32; off; off >>= 1){
    #pragma unroll
    for (int e = 0; e < NE; e++) acc[e] += __shfl_xor(acc[e], off);
  }
  if (lane == 0){
    float m = acc[0];
    #pragma unroll
    for (int e = 1; e < NE; e++) m = fmaxf(m, acc[e]);
    float p[NE], Z = 0.f;
    #pragma unroll
    for (int e = 0; e < NE; e++){ p[e] = expf(acc[e] - m); Z += p[e]; }
    float iZ = 1.f / Z;
    #pragma unroll
    for (int e = 0; e < NE; e++) p[e] *= iZ;
    int i1 = 0;
    #pragma unroll
    for (int e = 1; e < NE; e++) if (p[e] > p[i1]) i1 = e;
    int i2 = (i1 == 0) ? 1 : 0;
    #pragma unroll
    for (int e = 0; e < NE; e++) if (e != i1 && p[e] > p[i2]) i2 = e;
    float s2 = p[i1] + p[i2] + 1e-5f;
    int a1 = atomicAdd(&counts[i1], 1);
    lidx[(size_t)i1 * T + a1] = tok; lw[(size_t)i1 * T + a1] = p[i1] / s2;
    int a2 = atomicAdd(&counts[i2], 1);
    lidx[(size_t)i2 * T + a2] = tok; lw[(size_t)i2 * T + a2] = p[i2] / s2;
  }
}

// ---- pass A: fused gate+up GEMM + SiLU -> hidden (bf16, chunk-local rows) ----
__global__ __launch_bounds__(256, 2) void gateup_k(
    const void* __restrict__ x, const unsigned short* __restrict__ wgT, const unsigned short* __restrict__ wuT,
    const int* __restrict__ counts, int e, int T, const int* __restrict__ lidx,
    unsigned short* __restrict__ hidden, int chunk_off, const int* __restrict__ flag)
{
  int cnt = (e == NE) ? T : counts[e];
  int tm = blockIdx.y;
  if (chunk_off + tm * 128 >= cnt) return;
  int tn = blockIdx.x;
  int isf = *flag;

  __shared__ unsigned short Al[128 * 32];
  __shared__ unsigned short Bgl[128 * 32];
  __shared__ unsigned short Bul[128 * 32];

  int tid = threadIdx.x, wv = tid >> 6, lane = tid & 63;
  int c1 = cnt - 1;
  int r0 = chunk_off + tm * 128 + (tid >> 2);
  int r1 = r0 + 64;
  int rr0 = r0 < c1 ? r0 : c1, rr1 = r1 < c1 ? r1 : c1;
  int tok0 = (e == NE) ? rr0 : lidx[(size_t)e * T + rr0];
  int tok1 = (e == NE) ? rr1 : lidx[(size_t)e * T + rr1];
  int kc = (tid & 3) * 8;
  const unsigned short* ga0 = (const unsigned short*)x + (size_t)tok0 * H + kc;
  const unsigned short* ga1 = (const unsigned short*)x + (size_t)tok1 * H + kc;
  const float* fa0 = (const float*)x + (size_t)tok0 * H + kc;
  const float* fa1 = (const float*)x + (size_t)tok1 * H + kc;
  int nb = tn * 128 + (tid >> 2);
  const unsigned short* gg0 = wgT + (size_t)nb * H + kc;
  const unsigned short* gg1 = gg0 + (size_t)64 * H;
  const unsigned short* gu0 = wuT + (size_t)nb * H + kc;
  const unsigned short* gu1 = gu0 + (size_t)64 * H;

  f32x4 zero4 = {0.f, 0.f, 0.f, 0.f};
  f32x4 accg[4][4], accu[4][4];
  #pragma unroll
  for (int m = 0; m < 4; m++)
    #pragma unroll
    for (int n = 0; n < 4; n++){ accg[m][n] = zero4; accu[m][n] = zero4; }

  int wm = (wv >> 1) * 64, wn = (wv & 1) * 64;
  int rlo = lane & 15, khi = (lane >> 4) * 8;

  for (int k0 = 0; k0 < H; k0 += 32){
    if (isf){
      float4 q0 = *(const float4*)(fa0 + k0), q1 = *(const float4*)(fa0 + k0 + 4);
      float4 q2 = *(const float4*)(fa1 + k0), q3 = *(const float4*)(fa1 + k0 + 4);
      unsigned short w8[8];
      w8[0]=f2bf(q0.x); w8[1]=f2bf(q0.y); w8[2]=f2bf(q0.z); w8[3]=f2bf(q0.w);
      w8[4]=f2bf(q1.x); w8[5]=f2bf(q1.y); w8[6]=f2bf(q1.z); w8[7]=f2bf(q1.w);
      *(uint4*)(Al + tid * 8) = *(const uint4*)w8;
      w8[0]=f2bf(q2.x); w8[1]=f2bf(q2.y); w8[2]=f2bf(q2.z); w8[3]=f2bf(q2.w);
      w8[4]=f2bf(q3.x); w8[5]=f2bf(q3.y); w8[6]=f2bf(q3.z); w8[7]=f2bf(q3.w);
      *(uint4*)(Al + 2048 + tid * 8) = *(const uint4*)w8;
    } else {
      gload16(ga0 + k0, (char*)Al + wv * 1024);
      gload16(ga1 + k0, (char*)Al + 4096 + wv * 1024);
    }
    gload16(gg0 + k0, (char*)Bgl + wv * 1024);
    gload16(gg1 + k0, (char*)Bgl + 4096 + wv * 1024);
    gload16(gu0 + k0, (char*)Bul + wv * 1024);
    gload16(gu1 + k0, (char*)Bul + 4096 + wv * 1024);
    __syncthreads();
    short8 af[4], bg[4], bu[4];
    #pragma unroll
    for (int m = 0; m < 4; m++) af[m] = *(const short8*)(Al + (wm + m * 16 + rlo) * 32 + khi);
    #pragma unroll
    for (int n = 0; n < 4; n++){
      bg[n] = *(const short8*)(Bgl + (wn + n * 16 + rlo) * 32 + khi);
      bu[n] = *(const short8*)(Bul + (wn + n * 16 + rlo) * 32 + khi);
    }
    #pragma unroll
    for (int m = 0; m < 4; m++){
      #pragma unroll
      for (int n = 0; n < 4; n++){
        accg[m][n] = __builtin_amdgcn_mfma_f32_16x16x32_bf16(af[m], bg[n], accg[m][n], 0, 0, 0);
        accu[m][n] = __builtin_amdgcn_mfma_f32_16x16x32_bf16(af[m], bu[n], accu[m][n], 0, 0, 0);
      }
    }
    __syncthreads();
  }
  int rb = (lane >> 4) * 4, cb = lane & 15;
  #pragma unroll
  for (int m = 0; m < 4; m++){
    #pragma unroll
    for (int j = 0; j < 4; j++){
      int rl = tm * 128 + wm + m * 16 + rb + j;        // chunk-local row
      if (chunk_off + rl < cnt){
        unsigned short* hrow = hidden + (size_t)rl * ITR + tn * 128 + wn + cb;
        #pragma unroll
        for (int n = 0; n < 4; n++){
          float g = accg[m][n][j], u = accu[m][n][j];
          float h = g / (1.f + __expf(-g)) * u;
          hrow[n * 16] = f2bf(h);
        }
      }
    }
  }
}

// ---- pass B: down GEMM; shared(e==NE) plain-stores to out, routed RMW-accumulates ----
__global__ __launch_bounds__(256, 2) void down_k(
    const unsigned short* __restrict__ hidden, const unsigned short* __restrict__ wdT,
    const int* __restrict__ counts, int e, int T, const int* __restrict__ lidx,
    const float* __restrict__ lw, void* __restrict__ out_, int chunk_off,
    const int* __restrict__ flag, int CHc)
{
  int cnt = (e == NE) ? T : counts[e];
  int tm = blockIdx.y;
  if (chunk_off + tm * 128 >= cnt) return;
  int tn = blockIdx.x;
  int isf = *flag;
  int vcnt = cnt - chunk_off; if (vcnt > CHc) vcnt = CHc;

  __shared__ unsigned short Al[128 * 32];
  __shared__ unsigned short Bl[128 * 32];
  int tid = threadIdx.x, wv = tid >> 6, lane = tid & 63;
  int kc = (tid & 3) * 8;
  int vm1 = vcnt - 1;
  int lr0 = tm * 128 + (tid >> 2);
  int lr1 = lr0 + 64;
  int cl0 = lr0 < vm1 ? lr0 : vm1, cl1 = lr1 < vm1 ? lr1 : vm1;
  const unsigned short* ga0 = hidden + (size_t)cl0 * ITR + kc;
  const unsigned short* ga1 = hidden + (size_t)cl1 * ITR + kc;
  int nb = tn * 128 + (tid >> 2);
  const unsigned short* gb0 = wdT + (size_t)nb * ITR + kc;
  const unsigned short* gb1 = gb0 + (size_t)64 * ITR;

  f32x4 zero4 = {0.f, 0.f, 0.f, 0.f};
  f32x4 acc[4][4];
  #pragma unroll
  for (int m = 0; m < 4; m++)
    #pragma unroll
    for (int n = 0; n < 4; n++) acc[m][n] = zero4;

  int wm = (wv >> 1) * 64, wn = (wv & 1) * 64;
  int rlo = lane & 15, khi = (lane >> 4) * 8;

  for (int k0 = 0; k0 < ITR; k0 += 32){
    gload16(ga0 + k0, (char*)Al + wv * 1024);
    gload16(ga1 + k0, (char*)Al + 4096 + wv * 1024);
    gload16(gb0 + k0, (char*)Bl + wv * 1024);
    gload16(gb1 + k0, (char*)Bl + 4096 + wv * 1024);
    __syncthreads();
    short8 af[4], bf[4];
    #pragma unroll
    for (int m = 0; m < 4; m++) af[m] = *(const short8*)(Al + (wm + m * 16 + rlo) * 32 + khi);
    #pragma unroll
    for (int n = 0; n < 4; n++) bf[n] = *(const short8*)(Bl + (wn + n * 16 + rlo) * 32 + khi);
    #pragma unroll
    for (int m = 0; m < 4; m++){
      #pragma unroll
      for (int n = 0; n < 4; n++)
        acc[m][n] = __builtin_amdgcn_mfma_f32_16x16x32_bf16(af[m], bf[n], acc[m][n], 0, 0, 0);
    }
    __syncthreads();
  }
  int rb = (lane >> 4) * 4, cb = lane & 15;
  #pragma unroll
  for (int m = 0; m < 4; m++){
    #pragma unroll
    for (int j = 0; j < 4; j++){
      int rl = tm * 128 + wm + m * 16 + rb + j;        // chunk-local row
      if (rl < vcnt){
        int rg = chunk_off + rl;
        int tok = (e == NE) ? rg : lidx[(size_t)e * T + rg];
        size_t ob = (size_t)tok * H + tn * 128 + wn + cb;
        if (e == NE){
          if (isf){
            float* p = (float*)out_ + ob;
            #pragma unroll
            for (int n = 0; n < 4; n++) p[n * 16] = acc[m][n][j];
          } else {
            unsigned short* p = (unsigned short*)out_ + ob;
            #pragma unroll
            for (int n = 0; n < 4; n++) p[n * 16] = f2bf(acc[m][n][j]);
          }
        } else {
          float wgt = lw[(size_t)e * T + rg];
          if (isf){
            float* p = (float*)out_ + ob;
            #pragma unroll
            for (int n = 0; n < 4; n++) p[n * 16] += wgt * acc[m][n][j];
          } else {
            unsigned short* p = (unsigned short*)out_ + ob;
            #pragma unroll
            for (int n = 0; n < 4; n++) p[n * 16] = f2bf(bf2f(p[n * 16]) + wgt * acc[m][n][j]);
          }
        }
      }
    }
  }
}

extern "C" void kernel_launch(void* const* d_in, const int* in_sizes, int n_in,
                              void* d_out, int out_size, void* d_ws, size_t ws_size,
                              hipStream_t stream)
{
  int T = in_sizes[0] / H;   // 32768

  char* w = (char*)d_ws;
  auto alloc = [&](size_t b){ char* p = w; w += (b + 255) & ~(size_t)255; return p; };
  int* flag      = (int*)alloc(256);
  int* counts    = (int*)alloc(256);
  int* lidx      = (int*)alloc((size_t)NE * T * 4);
  float* lw      = (float*)alloc((size_t)NE * T * 4);
  unsigned short* wgT = (unsigned short*)alloc((size_t)ITR * H * 2);
  unsigned short* wuT = (unsigned short*)alloc((size_t)ITR * H * 2);
  unsigned short* wdT = (unsigned short*)alloc((size_t)H * ITR * 2);
  size_t fixed = (size_t)(w - (char*)d_ws);
  int CH = 8192;
  while (CH > 512 && fixed + (size_t)CH * ITR * 2 + 256 > ws_size) CH >>= 1;
  unsigned short* hidden = (unsigned short*)alloc((size_t)CH * ITR * 2);
  int NCH = (T + CH - 1) / CH;
  size_t EW = (size_t)H * ITR;     // elements per expert matrix

  detect_k<<<1, 64, 0, stream>>>((const unsigned int*)d_in[0], flag, counts);
  router_k<<<T / 4, 256, 0, stream>>>(d_in[0], d_in[1], d_in[2], d_in[3], T, flag, counts, lidx, lw);

  // shared expert first: plain stores fully initialize d_out
  trans3_k<<<dim3(32, 32, 3), 256, 0, stream>>>(d_in[7], d_in[8], d_in[9], 0, wgT, wuT, wdT, flag);
  for (int c = 0; c < NCH; c++){
    gateup_k<<<dim3(ITR / 128, CH / 128), 256, 0, stream>>>(
        d_in[0], wgT, wuT, counts, NE, T, lidx, hidden, c * CH, flag);
    down_k<<<dim3(H / 128, CH / 128), 256, 0, stream>>>(
        hidden, wdT, counts, NE, T, lidx, lw, d_out, c * CH, flag, CH);
  }
  // routed experts: stream one expert's transposed weights at a time
  for (int e = 0; e < NE; e++){
    trans3_k<<<dim3(32, 32, 3), 256, 0, stream>>>(d_in[4], d_in[5], d_in[6], (size_t)e * EW, wgT, wuT, wdT, flag);
    for (int c = 0; c < NCH; c++){
      gateup_k<<<dim3(ITR / 128, CH / 128), 256, 0, stream>>>(
          d_in[0], wgT, wuT, counts, e, T, lidx, hidden, c * CH, flag);
      down_k<<<dim3(H / 128, CH / 128), 256, 0, stream>>>(
          hidden, wdT, counts, e, T, lidx, lw, d_out, c * CH, flag, CH);
    }
  }
}

// Round 3
// 2800.489 us; speedup vs baseline: 1.2106x; 1.2106x over previous
//
#include <hip/hip_runtime.h>

#define H 1024
#define ITR 2048
#define NE 8
#define BT 128   // router tokens per block

typedef __attribute__((ext_vector_type(8))) short short8;
typedef __attribute__((ext_vector_type(4))) float f32x4;

__device__ __forceinline__ float bf2f(unsigned short u){
  union { unsigned int i; float f; } v; v.i = ((unsigned int)u) << 16; return v.f;
}
__device__ __forceinline__ unsigned short f2bf(float f){
  union { unsigned int i; float f; } v; v.f = f;
  unsigned int r = v.i + 0x7FFFu + ((v.i >> 16) & 1u);
  return (unsigned short)(r >> 16);
}
__device__ __forceinline__ void gload16(const void* g, void* l){
  __builtin_amdgcn_global_load_lds((const __attribute__((address_space(1))) void*)g,
                                   (__attribute__((address_space(3))) void*)l, 16, 0, 0);
}

// ---- dtype probe: bf16 => even-index ushorts have sane bf16 exponents. flag=1 => f32 storage.
__global__ __launch_bounds__(64) void detect_k(const unsigned int* __restrict__ xw,
                                               int* __restrict__ flag, int* __restrict__ counts){
  int lane = threadIdx.x;
  int c = 0;
  #pragma unroll
  for (int i = 0; i < 4; i++){
    unsigned u = xw[lane * 4 + i];
    int e = (u >> 7) & 0xFF;
    c += (e >= 100 && e <= 140) ? 1 : 0;
  }
  #pragma unroll
  for (int off = 32; off; off >>= 1) c += __shfl_xor(c, off);
  if (lane == 0) flag[0] = (c < 128) ? 1 : 0;
  if (lane < NE) counts[lane] = 0;
}

__device__ __forceinline__ void loadv16(const void* base, size_t off, int isf, float* out){
  if (isf){
    const float* p = (const float*)base + off;
    float4 a = *(const float4*)p, b = *(const float4*)(p + 4);
    float4 c = *(const float4*)(p + 8), d = *(const float4*)(p + 12);
    out[0]=a.x; out[1]=a.y; out[2]=a.z; out[3]=a.w;
    out[4]=b.x; out[5]=b.y; out[6]=b.z; out[7]=b.w;
    out[8]=c.x; out[9]=c.y; out[10]=c.z; out[11]=c.w;
    out[12]=d.x; out[13]=d.y; out[14]=d.z; out[15]=d.w;
  } else {
    const unsigned short* p = (const unsigned short*)base + off;
    uint4 a = *(const uint4*)p, b = *(const uint4*)(p + 8);
    unsigned short u[16];
    *(uint4*)u = a; *(uint4*)(u + 8) = b;
    #pragma unroll
    for (int j = 0; j < 16; j++) out[j] = bf2f(u[j]);
  }
}

// ---- transpose weights into bf16 slots; z = slot*3 + mtype (0=gate HxI,1=up HxI,2=down IxH)
__global__ __launch_bounds__(256) void trans_k(
    const void* __restrict__ rg, const void* __restrict__ ru, const void* __restrict__ rd,
    const void* __restrict__ sg, const void* __restrict__ su, const void* __restrict__ sd,
    int e0, unsigned short* __restrict__ arena, size_t slot_elems,
    const int* __restrict__ flag)
{
  int slot = blockIdx.z / 3, mt = blockIdx.z % 3;
  int e = e0 + slot;                       // e==NE => shared
  int R = (mt == 2) ? ITR : H;
  int C = (mt == 2) ? H : ITR;
  int c0 = blockIdx.x * 64, r0 = blockIdx.y * 64;
  if (c0 >= C || r0 >= R) return;
  const void* srcv;
  size_t eoff = 0;
  if (e == NE) srcv = (mt == 0) ? sg : ((mt == 1) ? su : sd);
  else { srcv = (mt == 0) ? rg : ((mt == 1) ? ru : rd); eoff = (size_t)e * H * ITR; }
  unsigned short* dst = arena + (size_t)slot * slot_elems + (size_t)mt * (H * ITR);
  int isf = *flag;
  __shared__ unsigned short tile[64][72];
  int t = threadIdx.x;
  int row = t >> 3, c8 = (t & 7) * 8;
  #pragma unroll
  for (int p = 0; p < 2; p++){
    int r = r0 + row + p * 32;
    unsigned short v[8];
    if (isf){
      const float* s = (const float*)srcv + eoff + (size_t)r * C + c0 + c8;
      float4 a = *(const float4*)s, b = *(const float4*)(s + 4);
      v[0]=f2bf(a.x); v[1]=f2bf(a.y); v[2]=f2bf(a.z); v[3]=f2bf(a.w);
      v[4]=f2bf(b.x); v[5]=f2bf(b.y); v[6]=f2bf(b.z); v[7]=f2bf(b.w);
    } else {
      const unsigned short* s = (const unsigned short*)srcv + eoff + (size_t)r * C + c0 + c8;
      *(uint4*)v = *(const uint4*)s;
    }
    *(uint4*)&tile[row + p * 32][c8] = *(const uint4*)v;
  }
  __syncthreads();
  #pragma unroll
  for (int p = 0; p < 2; p++){
    int c = row + p * 32;
    unsigned short tmp[8];
    #pragma unroll
    for (int j = 0; j < 8; j++) tmp[j] = tile[c8 + j][c];
    *(uint4*)(dst + (size_t)(c0 + c) * R + r0 + c8) = *(const uint4*)tmp;
  }
}

// ---- hierarchical router: LDS-aggregated counts, one global atomic per expert per block ----
__global__ __launch_bounds__(256) void router2_k(
    const void* __restrict__ x, const void* __restrict__ lns, const void* __restrict__ lnb,
    const void* __restrict__ gw, int T, const int* __restrict__ flag,
    int* __restrict__ counts, int* __restrict__ lidx, float* __restrict__ lw)
{
  int isf = *flag;
  int tid = threadIdx.x, wv = tid >> 6, lane = tid & 63;
  int t0 = blockIdx.x * BT;
  __shared__ int sc_cnt[NE], sbase[NE];
  __shared__ int se1[BT], se2[BT], so1[BT], so2[BT];
  __shared__ float sw1[BT], sw2[BT];
  if (tid < NE) sc_cnt[tid] = 0;
  float sc[16], bi[16];
  loadv16(lns, (size_t)lane * 16, isf, sc);
  loadv16(lnb, (size_t)lane * 16, isf, bi);
  __syncthreads();

  for (int i = 0; i < BT / 4; i++){
    int tl = i * 4 + wv;
    int tok = t0 + tl;
    if (tok >= T) break;
    float v[16];
    loadv16(x, (size_t)tok * H + lane * 16, isf, v);
    float sum = 0.f, ss = 0.f;
    #pragma unroll
    for (int j = 0; j < 16; j++){ sum += v[j]; ss += v[j] * v[j]; }
    #pragma unroll
    for (int off = 32; off; off >>= 1){ sum += __shfl_xor(sum, off); ss += __shfl_xor(ss, off); }
    float mu = sum * (1.f / H);
    float rstd = rsqrtf(ss * (1.f / H) - mu * mu + 1e-5f);
    float xn[16];
    #pragma unroll
    for (int j = 0; j < 16; j++) xn[j] = (v[j] - mu) * rstd * sc[j] + bi[j];
    float acc[NE];
    #pragma unroll
    for (int e = 0; e < NE; e++){
      float g[16];
      loadv16(gw, (size_t)e * H + lane * 16, isf, g);
      float s = 0.f;
      #pragma unroll
      for (int j = 0; j < 16; j++) s += xn[j] * g[j];
      acc[e] = s;
    }
    #pragma unroll
    for (int off = 32; off; off >>= 1){
      #pragma unroll
      for (int e = 0; e < NE; e++) acc[e] += __shfl_xor(acc[e], off);
    }
    if (lane == 0){
      float m = acc[0];
      #pragma unroll
      for (int e = 1; e < NE; e++) m = fmaxf(m, acc[e]);
      float p[NE], Z = 0.f;
      #pragma unroll
      for (int e = 0; e < NE; e++){ p[e] = expf(acc[e] - m); Z += p[e]; }
      float iZ = 1.f / Z;
      #pragma unroll
      for (int e = 0; e < NE; e++) p[e] *= iZ;
      int i1 = 0;
      #pragma unroll
      for (int e = 1; e < NE; e++) if (p[e] > p[i1]) i1 = e;
      int i2 = (i1 == 0) ? 1 : 0;
      #pragma unroll
      for (int e = 0; e < NE; e++) if (e != i1 && p[e] > p[i2]) i2 = e;
      float s2 = p[i1] + p[i2] + 1e-5f;
      int o1 = atomicAdd(&sc_cnt[i1], 1);
      int o2 = atomicAdd(&sc_cnt[i2], 1);
      se1[tl] = i1; so1[tl] = o1; sw1[tl] = p[i1] / s2;
      se2[tl] = i2; so2[tl] = o2; sw2[tl] = p[i2] / s2;
    }
  }
  __syncthreads();
  if (tid < NE) sbase[tid] = atomicAdd(&counts[tid], sc_cnt[tid]);
  __syncthreads();
  if (tid < BT && t0 + tid < T){
    int tok = t0 + tid;
    int e1 = se1[tid], p1 = sbase[e1] + so1[tid];
    lidx[(size_t)e1 * T + p1] = tok; lw[(size_t)e1 * T + p1] = sw1[tid];
    int e2 = se2[tid], p2 = sbase[e2] + so2[tid];
    lidx[(size_t)e2 * T + p2] = tok; lw[(size_t)e2 * T + p2] = sw2[tid];
  }
}

// ---- pass A: fused gate+up GEMM + SiLU -> hidden (bf16, chunk-local rows) ----
__global__ __launch_bounds__(256, 2) void gateup_k(
    const void* __restrict__ x, const unsigned short* __restrict__ wgT, const unsigned short* __restrict__ wuT,
    const int* __restrict__ counts, int e, int T, const int* __restrict__ lidx,
    unsigned short* __restrict__ hidden, int chunk_off, const int* __restrict__ flag)
{
  int cnt = (e == NE) ? T : counts[e];
  int tm = blockIdx.y;
  if (chunk_off + tm * 128 >= cnt) return;
  int tn = blockIdx.x;
  int isf = *flag;

  __shared__ unsigned short Al[128 * 32];
  __shared__ unsigned short Bgl[128 * 32];
  __shared__ unsigned short Bul[128 * 32];

  int tid = threadIdx.x, wv = tid >> 6, lane = tid & 63;
  int c1 = cnt - 1;
  int r0 = chunk_off + tm * 128 + (tid >> 2);
  int r1 = r0 + 64;
  int rr0 = r0 < c1 ? r0 : c1, rr1 = r1 < c1 ? r1 : c1;
  int tok0 = (e == NE) ? rr0 : lidx[(size_t)e * T + rr0];
  int tok1 = (e == NE) ? rr1 : lidx[(size_t)e * T + rr1];
  int kc = (tid & 3) * 8;
  const unsigned short* ga0 = (const unsigned short*)x + (size_t)tok0 * H + kc;
  const unsigned short* ga1 = (const unsigned short*)x + (size_t)tok1 * H + kc;
  const float* fa0 = (const float*)x + (size_t)tok0 * H + kc;
  const float* fa1 = (const float*)x + (size_t)tok1 * H + kc;
  int nb = tn * 128 + (tid >> 2);
  const unsigned short* gg0 = wgT + (size_t)nb * H + kc;
  const unsigned short* gg1 = gg0 + (size_t)64 * H;
  const unsigned short* gu0 = wuT + (size_t)nb * H + kc;
  const unsigned short* gu1 = gu0 + (size_t)64 * H;

  f32x4 zero4 = {0.f, 0.f, 0.f, 0.f};
  f32x4 accg[4][4], accu[4][4];
  #pragma unroll
  for (int m = 0; m < 4; m++)
    #pragma unroll
    for (int n = 0; n < 4; n++){ accg[m][n] = zero4; accu[m][n] = zero4; }

  int wm = (wv >> 1) * 64, wn = (wv & 1) * 64;
  int rlo = lane & 15, khi = (lane >> 4) * 8;

  for (int k0 = 0; k0 < H; k0 += 32){
    if (isf){
      float4 q0 = *(const float4*)(fa0 + k0), q1 = *(const float4*)(fa0 + k0 + 4);
      float4 q2 = *(const float4*)(fa1 + k0), q3 = *(const float4*)(fa1 + k0 + 4);
      unsigned short w8[8];
      w8[0]=f2bf(q0.x); w8[1]=f2bf(q0.y); w8[2]=f2bf(q0.z); w8[3]=f2bf(q0.w);
      w8[4]=f2bf(q1.x); w8[5]=f2bf(q1.y); w8[6]=f2bf(q1.z); w8[7]=f2bf(q1.w);
      *(uint4*)(Al + tid * 8) = *(const uint4*)w8;
      w8[0]=f2bf(q2.x); w8[1]=f2bf(q2.y); w8[2]=f2bf(q2.z); w8[3]=f2bf(q2.w);
      w8[4]=f2bf(q3.x); w8[5]=f2bf(q3.y); w8[6]=f2bf(q3.z); w8[7]=f2bf(q3.w);
      *(uint4*)(Al + 2048 + tid * 8) = *(const uint4*)w8;
    } else {
      gload16(ga0 + k0, (char*)Al + wv * 1024);
      gload16(ga1 + k0, (char*)Al + 4096 + wv * 1024);
    }
    gload16(gg0 + k0, (char*)Bgl + wv * 1024);
    gload16(gg1 + k0, (char*)Bgl + 4096 + wv * 1024);
    gload16(gu0 + k0, (char*)Bul + wv * 1024);
    gload16(gu1 + k0, (char*)Bul + 4096 + wv * 1024);
    __syncthreads();
    short8 af[4], bg[4], bu[4];
    #pragma unroll
    for (int m = 0; m < 4; m++) af[m] = *(const short8*)(Al + (wm + m * 16 + rlo) * 32 + khi);
    #pragma unroll
    for (int n = 0; n < 4; n++){
      bg[n] = *(const short8*)(Bgl + (wn + n * 16 + rlo) * 32 + khi);
      bu[n] = *(const short8*)(Bul + (wn + n * 16 + rlo) * 32 + khi);
    }
    #pragma unroll
    for (int m = 0; m < 4; m++){
      #pragma unroll
      for (int n = 0; n < 4; n++){
        accg[m][n] = __builtin_amdgcn_mfma_f32_16x16x32_bf16(af[m], bg[n], accg[m][n], 0, 0, 0);
        accu[m][n] = __builtin_amdgcn_mfma_f32_16x16x32_bf16(af[m], bu[n], accu[m][n], 0, 0, 0);
      }
    }
    __syncthreads();
  }
  int rb = (lane >> 4) * 4, cb = lane & 15;
  #pragma unroll
  for (int m = 0; m < 4; m++){
    #pragma unroll
    for (int j = 0; j < 4; j++){
      int rl = tm * 128 + wm + m * 16 + rb + j;
      if (chunk_off + rl < cnt){
        unsigned short* hrow = hidden + (size_t)rl * ITR + tn * 128 + wn + cb;
        #pragma unroll
        for (int n = 0; n < 4; n++){
          float g = accg[m][n][j], u = accu[m][n][j];
          float h = g / (1.f + __expf(-g)) * u;
          hrow[n * 16] = f2bf(h);
        }
      }
    }
  }
}

// ---- pass B: down GEMM; shared(e==NE) plain-stores to out, routed RMW-accumulates ----
__global__ __launch_bounds__(256, 2) void down_k(
    const unsigned short* __restrict__ hidden, const unsigned short* __restrict__ wdT,
    const int* __restrict__ counts, int e, int T, const int* __restrict__ lidx,
    const float* __restrict__ lw, void* __restrict__ out_, int chunk_off,
    const int* __restrict__ flag, int CHc)
{
  int cnt = (e == NE) ? T : counts[e];
  int tm = blockIdx.y;
  if (chunk_off + tm * 128 >= cnt) return;
  int tn = blockIdx.x;
  int isf = *flag;
  int vcnt = cnt - chunk_off; if (vcnt > CHc) vcnt = CHc;

  __shared__ unsigned short Al[128 * 32];
  __shared__ unsigned short Bl[128 * 32];
  int tid = threadIdx.x, wv = tid >> 6, lane = tid & 63;
  int kc = (tid & 3) * 8;
  int vm1 = vcnt - 1;
  int lr0 = tm * 128 + (tid >> 2);
  int lr1 = lr0 + 64;
  int cl0 = lr0 < vm1 ? lr0 : vm1, cl1 = lr1 < vm1 ? lr1 : vm1;
  const unsigned short* ga0 = hidden + (size_t)cl0 * ITR + kc;
  const unsigned short* ga1 = hidden + (size_t)cl1 * ITR + kc;
  int nb = tn * 128 + (tid >> 2);
  const unsigned short* gb0 = wdT + (size_t)nb * ITR + kc;
  const unsigned short* gb1 = gb0 + (size_t)64 * ITR;

  f32x4 zero4 = {0.f, 0.f, 0.f, 0.f};
  f32x4 acc[4][4];
  #pragma unroll
  for (int m = 0; m < 4; m++)
    #pragma unroll
    for (int n = 0; n < 4; n++) acc[m][n] = zero4;

  int wm = (wv >> 1) * 64, wn = (wv & 1) * 64;
  int rlo = lane & 15, khi = (lane >> 4) * 8;

  for (int k0 = 0; k0 < ITR; k0 += 32){
    gload16(ga0 + k0, (char*)Al + wv * 1024);
    gload16(ga1 + k0, (char*)Al + 4096 + wv * 1024);
    gload16(gb0 + k0, (char*)Bl + wv * 1024);
    gload16(gb1 + k0, (char*)Bl + 4096 + wv * 1024);
    __syncthreads();
    short8 af[4], bf[4];
    #pragma unroll
    for (int m = 0; m < 4; m++) af[m] = *(const short8*)(Al + (wm + m * 16 + rlo) * 32 + khi);
    #pragma unroll
    for (int n = 0; n < 4; n++) bf[n] = *(const short8*)(Bl + (wn + n * 16 + rlo) * 32 + khi);
    #pragma unroll
    for (int m = 0; m < 4; m++){
      #pragma unroll
      for (int n = 0; n < 4; n++)
        acc[m][n] = __builtin_amdgcn_mfma_f32_16x16x32_bf16(af[m], bf[n], acc[m][n], 0, 0, 0);
    }
    __syncthreads();
  }
  int rb = (lane >> 4) * 4, cb = lane & 15;
  #pragma unroll
  for (int m = 0; m < 4; m++){
    #pragma unroll
    for (int j = 0; j < 4; j++){
      int rl = tm * 128 + wm + m * 16 + rb + j;
      if (rl < vcnt){
        int rg = chunk_off + rl;
        int tok = (e == NE) ? rg : lidx[(size_t)e * T + rg];
        size_t ob = (size_t)tok * H + tn * 128 + wn + cb;
        if (e == NE){
          if (isf){
            float* p = (float*)out_ + ob;
            #pragma unroll
            for (int n = 0; n < 4; n++) p[n * 16] = acc[m][n][j];
          } else {
            unsigned short* p = (unsigned short*)out_ + ob;
            #pragma unroll
            for (int n = 0; n < 4; n++) p[n * 16] = f2bf(acc[m][n][j]);
          }
        } else {
          float wgt = lw[(size_t)e * T + rg];
          if (isf){
            float* p = (float*)out_ + ob;
            #pragma unroll
            for (int n = 0; n < 4; n++) p[n * 16] += wgt * acc[m][n][j];
          } else {
            unsigned short* p = (unsigned short*)out_ + ob;
            #pragma unroll
            for (int n = 0; n < 4; n++) p[n * 16] = f2bf(bf2f(p[n * 16]) + wgt * acc[m][n][j]);
          }
        }
      }
    }
  }
}

extern "C" void kernel_launch(void* const* d_in, const int* in_sizes, int n_in,
                              void* d_out, int out_size, void* d_ws, size_t ws_size,
                              hipStream_t stream)
{
  int T = in_sizes[0] / H;   // 32768

  char* w = (char*)d_ws;
  auto alloc = [&](size_t b){ char* p = w; w += (b + 255) & ~(size_t)255; return p; };
  int* flag   = (int*)alloc(256);
  int* counts = (int*)alloc(256);
  int* lidx   = (int*)alloc((size_t)NE * T * 4);
  float* lw   = (float*)alloc((size_t)NE * T * 4);
  size_t base = (size_t)(w - (char*)d_ws);

  const size_t SLOT = (size_t)3 * H * ITR;            // elements per expert trio
  const size_t SLOTB = SLOT * 2;                      // bytes

  // pick mode + chunk size from ws_size (largest CH that fits)
  int full = 0, CH = 0;
  for (int ch = 8192; ch >= 512; ch >>= 1){
    if (base + 9 * SLOTB + (size_t)ch * ITR * 2 + 1024 <= ws_size){ full = 1; CH = ch; break; }
  }
  if (!full){
    CH = 512;
    for (int ch = 8192; ch >= 512; ch >>= 1){
      if (base + SLOTB + (size_t)ch * ITR * 2 + 1024 <= ws_size){ CH = ch; break; }
    }
  }
  int nslots = full ? 9 : 1;
  unsigned short* arena = (unsigned short*)alloc((size_t)nslots * SLOTB);
  unsigned short* hidden = (unsigned short*)alloc((size_t)CH * ITR * 2);
  int NCH = (T + CH - 1) / CH;

  detect_k<<<1, 64, 0, stream>>>((const unsigned int*)d_in[0], flag, counts);
  router2_k<<<(T + BT - 1) / BT, 256, 0, stream>>>(d_in[0], d_in[1], d_in[2], d_in[3],
                                                   T, flag, counts, lidx, lw);

  auto run_expert = [&](int e, int slot){
    unsigned short* wgT = arena + (size_t)slot * SLOT;
    unsigned short* wuT = wgT + (size_t)H * ITR;
    unsigned short* wdT = wuT + (size_t)H * ITR;
    for (int c = 0; c < NCH; c++){
      gateup_k<<<dim3(ITR / 128, CH / 128), 256, 0, stream>>>(
          d_in[0], wgT, wuT, counts, e, T, lidx, hidden, c * CH, flag);
      down_k<<<dim3(H / 128, CH / 128), 256, 0, stream>>>(
          hidden, wdT, counts, e, T, lidx, lw, d_out, c * CH, flag, CH);
    }
  };

  if (full){
    // transpose all 9 expert trios in one dispatch (slots 0..7 routed, slot 8 shared)
    trans_k<<<dim3(32, 32, 27), 256, 0, stream>>>(d_in[4], d_in[5], d_in[6],
                                                  d_in[7], d_in[8], d_in[9],
                                                  0, arena, SLOT, flag);
    run_expert(NE, 8);                          // shared first: plain stores init out
    for (int e = 0; e < NE; e++) run_expert(e, e);
  } else {
    // streaming: one slot, transpose per expert
    trans_k<<<dim3(32, 32, 3), 256, 0, stream>>>(d_in[4], d_in[5], d_in[6],
                                                 d_in[7], d_in[8], d_in[9],
                                                 NE, arena, SLOT, flag);   // shared into slot 0
    run_expert(NE, 0);
    for (int e = 0; e < NE; e++){
      trans_k<<<dim3(32, 32, 3), 256, 0, stream>>>(d_in[4], d_in[5], d_in[6],
                                                   d_in[7], d_in[8], d_in[9],
                                                   e, arena, SLOT, flag);
      run_expert(e, 0);
    }
  }
}